// Round 2
// baseline (1392.820 us; speedup 1.0000x reference)
//
#include <hip/hip_runtime.h>
#include <math.h>

// Problem constants (N=2, C=64, H=96, W=96, PATCH=3)
static constexpr int NITEM = 2;
static constexpr int C = 64;
static constexpr int H = 96;
static constexpr int W = 96;
static constexpr int HW = H * W;        // 9216
static constexpr int HP = 94;           // H - 3 + 1
static constexpr int NP = HP * HP;      // 8836

// Piece decomposition: per (n, dy) split valid yi-range into 16-row pieces.
// Sum over dy of ceil(nyi/16) = 642 per item (nyi = 94-|dy|).
static constexpr int PL = 16;           // piece length (yi rows)
static constexpr int PIECES_PER_N = 642;
static constexpr int NPIECES = NITEM * PIECES_PER_N;   // 1284
static constexpr int NBLOCKS = 1024;    // 2 blocks/CU x 256 CU slots, ticket-drained

// Order-preserving fp32 -> uint32 (v1 > v2  <=>  key(v1) > key(v2))
__device__ __forceinline__ unsigned int fkey(float v) {
    unsigned int u = __float_as_uint(v);
    return (u & 0x80000000u) ? ~u : (u | 0x80000000u);
}

__device__ __forceinline__ unsigned long long shflx64(unsigned long long v, int m) {
    int lo = __shfl_xor((int)(unsigned int)v, m);
    int hi = __shfl_xor((int)(unsigned int)(v >> 32), m);
    return ((unsigned long long)(unsigned int)hi << 32) | (unsigned int)lo;
}

// ---------------- Kernel 1: per-pixel channel L2 normalize + NCHW->NHWC ----------------
__global__ __launch_bounds__(256) void normalize_kernel(
    const float* __restrict__ f1, const float* __restrict__ f2,
    float* __restrict__ fiN, float* __restrict__ frN, float* __restrict__ ssn)
{
    int t = blockIdx.x * 256 + threadIdx.x;
    const int perTensor = NITEM * HW;
    if (t >= 2 * perTensor) return;
    int which = t / perTensor;
    int p = t - which * perTensor;
    int n = p / HW;
    int pix = p - n * HW;
    const float* src = (which ? f2 : f1) + (size_t)n * C * HW + pix;
    float s = 0.f;
    #pragma unroll
    for (int c = 0; c < C; c++) {
        float v = src[c * HW];
        s = fmaf(v, v, s);
    }
    float norm = sqrtf(s);
    float scale = 1.0f / fmaxf(norm, 1e-12f);
    float* dst = (which ? frN : fiN) + (size_t)p * C;
    #pragma unroll
    for (int c = 0; c < C; c++) {
        dst[c] = src[c * HW] * scale;
    }
    if (which) ssn[p] = s * scale * scale;
}

// ---------------- Kernel 2: ref patch inverse norms ----------------
__global__ __launch_bounds__(256) void refnorm_kernel(
    const float* __restrict__ ssn, float* __restrict__ invn)
{
    int t = blockIdx.x * 256 + threadIdx.x;
    if (t >= NITEM * NP) return;
    int n = t / NP;
    int r = t - n * NP;
    int yr = r / HP, xr = r - yr * HP;
    const float* s = ssn + n * HW;
    float acc = 0.f;
    #pragma unroll
    for (int dy = 0; dy < 3; dy++)
        #pragma unroll
        for (int dx = 0; dx < 3; dx++)
            acc += s[(yr + dy) * W + (xr + dx)];
    invn[t] = 1.0f / (sqrtf(acc) + 1e-5f);
}

// ---------------- Kernel 3: skewed-coordinate fused cost-volume + argmax ----------------
// Per (n, dy, yi-piece): for each pixel-row y, compute the row-pair GEMM directly in
// skewed coords G'[u][delta] = dot(fi[y][u], fr[y+dy][u-delta]) held in REGISTERS
// (6 u x 7 delta fragment per thread; 16 u-groups x 16 delta-lanes, lane l=15 idle).
// The 3-tap x-sum B[xi][d] = G'[xi]+G'[xi+1]+G'[xi+2] is then a within-thread vertical
// sum; rows u0+6, u0+7 come from the next u-group via a small LDS side-channel (each
// group publishes its rows 0,1). The y-tap uses the same pA/pB register rotation as
// before; finalize = (pA+Bv)*inv, per-xi argmax over delta-lanes via shfl, atomicMax.
// Garbage cells (v or delta out of range) only ever feed masked outputs: any B passing
// the xr-in-[0,94) mask uses v = xr..xr+2, all valid.
// Association matches the prior passing kernels exactly: ascending-c fmaf chain,
// (g0+g1)+g2 over dx, ((B0+B1)+B2)*inv over dy -> bit-identical corr values.
// Dynamic ticket scheduling over 1284 ~uniform pieces fixes the tail imbalance.
__global__ __launch_bounds__(256, 2) void corr_skew_kernel(
    const float* __restrict__ fiN, const float* __restrict__ frN,
    const float* __restrict__ invn, unsigned long long* __restrict__ best,
    unsigned int* __restrict__ tick)
{
    // LDS: Ap 24832 + Bp 28928 + sh 14552 + ctl ~16 = ~68.3 KB -> 2 blocks/CU.
    __shared__ struct {
        float4 Ap[16][97];      // fi row, [cq][u], stride 97 (dword coeff 388%32=4)
        float4 Bp[16][113];     // fr row, [cq][9+v], guards v in [-9, 100]
        float  sh[17 * 2 * 107];// halo rows: [(gg*2+r)*107 + deltaIdx], gg=0..16
        int    sp;
    } sm;

    const int t = threadIdx.x;
    const int g = t >> 4;            // u-group: u0 = 6g (16 groups cover u 0..95)
    const int l = t & 15;            // delta lane; l==15 idle (15*7=105 >= 101 needed)
    const int u0 = 6 * g;
    // per-thread delta origin: delta0 = u0 - 95 + 7l  (coverage [u0-95, u0+10))
    // b-window: v = u0 + i - (delta0 + j) = S + i - j, S = 95 - 7l; slot = 6+i-j in [0,11]
    const int vb = 98 - 7 * l;       // Bp col of slot 0 = 9 + (S-6) = 98-7l (l=14 -> 0)

    float pA[6][7], pB[6][7];

    while (true) {
        if (t == 0) sm.sp = (int)atomicAdd(tick, 1u);
        __syncthreads();
        const int p = sm.sp;
        if (p >= NPIECES) break;

        // ---- decode piece -> (n, dy, ya, nb) (uniform across block) ----
        int n = p / PIECES_PER_N;
        int r = p - n * PIECES_PER_N;
        int dy = 0, ya = 0, nb = 0;
        for (int d = 0; d < 187; ++d) {
            int ady = d < 93 ? 93 - d : d - 93;
            int nyi = 94 - ady;
            int q = (nyi + PL - 1) / PL;
            if (r < q) {
                dy = d - 93;
                ya = (dy < 0 ? -dy : 0) + r * PL;
                nb = nyi - r * PL; if (nb > PL) nb = PL;
                break;
            }
            r -= q;
        }
        const int yb = ya + nb;      // finalize yi in [ya, yb); y runs ya..yb+1

        const float* fa = fiN + (size_t)n * HW * C;
        const float* fb = frN + (size_t)n * HW * C;
        const float* inv = invn + (size_t)n * NP;
        unsigned long long* bn = best + (size_t)n * NP;

        // ---- prologue: stage rows (ya, ya+dy) ----
        {
            const float* pfa = fa + (size_t)ya * (W * C);
            const float* pfb = fb + (size_t)(ya + dy) * (W * C);
            float4 xa[6], xb[6];
            #pragma unroll
            for (int j = 0; j < 6; j++) {
                int id = t + 256 * j; int u = id >> 4; int cq = id & 15;
                xa[j] = *(const float4*)(pfa + u * C + cq * 4);
                xb[j] = *(const float4*)(pfb + u * C + cq * 4);
            }
            #pragma unroll
            for (int j = 0; j < 6; j++) {
                int id = t + 256 * j; int u = id >> 4; int cq = id & 15;
                sm.Ap[cq][u] = xa[j];
                sm.Bp[cq][9 + u] = xb[j];
            }
        }
        __syncthreads();

        for (int y = ya; y <= yb + 1; ++y) {
            const bool doLd = (y <= yb);
            const bool doFin = (y >= ya + 2);
            const bool doA = (y > ya);
            const int yi = y - 2;
            const int yr = yi + dy;

            // ---- skewed GEMM: acc[i][j] = G'[u0+i][delta0+j], K=64 ----
            float acc[6][7];
            #pragma unroll
            for (int i = 0; i < 6; i++)
                #pragma unroll
                for (int j = 0; j < 7; j++) acc[i][j] = 0.f;

            if (l < 15) {
                const float4* ap = &sm.Ap[0][u0];
                const float4* bp = &sm.Bp[0][vb];
                #pragma unroll 2
                for (int cq = 0; cq < 16; ++cq) {
                    float4 a[6], w[12];
                    #pragma unroll
                    for (int i = 0; i < 6; i++) a[i] = ap[i];
                    #pragma unroll
                    for (int m = 0; m < 12; m++) w[m] = bp[m];
                    #pragma unroll
                    for (int i = 0; i < 6; i++)
                        #pragma unroll
                        for (int j = 0; j < 7; j++) {
                            const float4 b = w[6 + i - j];  // v = S+i-j
                            acc[i][j] = fmaf(a[i].x, b.x, acc[i][j]);
                            acc[i][j] = fmaf(a[i].y, b.y, acc[i][j]);
                            acc[i][j] = fmaf(a[i].z, b.z, acc[i][j]);
                            acc[i][j] = fmaf(a[i].w, b.w, acc[i][j]);
                        }
                    ap += 97; bp += 113;
                }
                // publish halo rows 0,1 for predecessor group
                #pragma unroll
                for (int j = 0; j < 7; j++) {
                    sm.sh[(2 * g + 0) * 107 + 7 * l + j] = acc[0][j];
                    sm.sh[(2 * g + 1) * 107 + 7 * l + j] = acc[1][j];
                }
            }

            // issue next-row loads (latency hidden by barrier + other block)
            float4 xa[6], xb[6];
            if (doLd) {
                const float* pfa = fa + (size_t)(y + 1) * (W * C);
                const float* pfb = fb + (size_t)(y + 1 + dy) * (W * C);
                #pragma unroll
                for (int j = 0; j < 6; j++) {
                    int id = t + 256 * j; int u = id >> 4; int cq = id & 15;
                    xa[j] = *(const float4*)(pfa + u * C + cq * 4);
                    xb[j] = *(const float4*)(pfb + u * C + cq * 4);
                }
            }
            __syncthreads();     // (1) halo visible; panels no longer read
            if (doLd) {
                #pragma unroll
                for (int j = 0; j < 6; j++) {
                    int id = t + 256 * j; int u = id >> 4; int cq = id & 15;
                    sm.Ap[cq][u] = xa[j];
                    sm.Bp[cq][9 + u] = xb[j];
                }
            }

            // ---- taps + rotate + finalize yi = y-2 ----
            float ivr[12];
            if (doFin && l < 15) {
                const float* ivp = inv + (size_t)yr * HP;
                #pragma unroll
                for (int m = 0; m < 12; m++) {
                    int xr = 89 - 7 * l + m;
                    xr = xr < 0 ? 0 : (xr > 93 ? 93 : xr);
                    ivr[m] = ivp[xr];
                }
            }

            unsigned long long keys[6];
            #pragma unroll
            for (int i = 0; i < 6; i++) {
                unsigned long long k = 0ULL;
                if (l < 15) {
                    float Bv[7];
                    #pragma unroll
                    for (int j = 0; j < 7; j++) {
                        if (i <= 3) {
                            Bv[j] = (acc[i][j] + acc[i + 1][j]) + acc[i + 2][j];
                        } else {
                            int idx = 7 * l + j - 6; idx = idx < 0 ? 0 : idx;
                            float s0 = sm.sh[((g + 1) * 2 + 0) * 107 + idx];
                            if (i == 4) {
                                Bv[j] = (acc[4][j] + acc[5][j]) + s0;
                            } else {
                                float s1 = sm.sh[((g + 1) * 2 + 1) * 107 + idx];
                                Bv[j] = (acc[5][j] + s0) + s1;
                            }
                        }
                    }
                    if (doFin) {
                        float bv = -INFINITY; int bx = 0;
                        #pragma unroll
                        for (int jj = 6; jj >= 0; --jj) {   // j desc -> xr ascending (tie: min xr)
                            int slot = 6 + i - jj;
                            int xr = 89 - 7 * l + slot;
                            float v = (pA[i][jj] + Bv[jj]) * ivr[slot];
                            bool ok = (xr >= 0) && (xr < HP) && (u0 + i < HP);
                            if (ok && v > bv) { bv = v; bx = xr; }
                        }
                        k = ((unsigned long long)fkey(bv) << 32)
                          | (unsigned int)(~(unsigned int)(yr * HP + bx));
                    }
                    #pragma unroll
                    for (int j = 0; j < 7; j++) {
                        if (doA) pA[i][j] = pB[i][j] + Bv[j];
                        pB[i][j] = Bv[j];
                    }
                }
                keys[i] = k;
            }

            if (doFin) {
                #pragma unroll
                for (int i = 0; i < 6; i++) {
                    unsigned long long k = keys[i];
                    #pragma unroll
                    for (int m = 1; m < 16; m <<= 1) {
                        unsigned long long o = shflx64(k, m);
                        if (o > k) k = o;
                    }
                    keys[i] = k;
                }
                if (l < 6 && (u0 + l) < HP) {
                    unsigned long long sel =
                        l == 0 ? keys[0] : l == 1 ? keys[1] : l == 2 ? keys[2] :
                        l == 3 ? keys[3] : l == 4 ? keys[4] : keys[5];
                    atomicMax(&bn[(size_t)yi * HP + u0 + l], sel);
                }
            }
            __syncthreads();     // (2) panel writes visible; halo safe to rewrite
        }
    }
}

// ---------------- Kernel 4: expand to 9 shifted copies, channel-interleaved ----------------
__global__ __launch_bounds__(256) void expand_best_kernel(
    const unsigned long long* __restrict__ best, float* __restrict__ out)
{
    int t = blockIdx.x * 256 + threadIdx.x;
    const int total = NITEM * 18 * HW;
    if (t >= total) return;
    int x = t % W;
    int y = (t / W) % H;
    int chn = (t / HW) % 18;
    int n = t / (18 * HW);
    int k = chn >> 1;
    int b = chn & 1;          // 0 -> flow_h, 1 -> flow_w
    int is = k / 3, js = k - is * 3;
    int ys = y - is, xs = x - js;
    float val = 0.f;
    if (ys >= 0 && ys < HP && xs >= 0 && xs < HP) {
        int i = ys * HP + xs;
        unsigned long long key = best[(size_t)n * NP + i];
        int idx = (int)(~(unsigned int)key);
        int yr = idx / HP, xr = idx - yr * HP;
        val = b ? (float)(xr - xs) : (float)(yr - ys);
    }
    out[t] = val;
}

// ---------------- Launch ----------------
extern "C" void kernel_launch(void* const* d_in, const int* in_sizes, int n_in,
                              void* d_out, int out_size, void* d_ws, size_t ws_size,
                              hipStream_t stream) {
    (void)in_sizes; (void)n_in; (void)out_size; (void)ws_size;
    const float* f1 = (const float*)d_in[0];
    const float* f2 = (const float*)d_in[1];
    float* ws = (float*)d_ws;

    float* fiN  = ws;                                   // 2*9216*64
    float* frN  = fiN + (size_t)NITEM * HW * C;         // 2*9216*64
    float* ssn  = frN + (size_t)NITEM * HW * C;         // 2*9216
    float* invn = ssn + (size_t)NITEM * HW;             // 2*8836
    unsigned long long* best =
        (unsigned long long*)((((uintptr_t)(invn + (size_t)NITEM * NP)) + 63) & ~(uintptr_t)63);
    unsigned int* tick = (unsigned int*)(best + (size_t)NITEM * NP);
    // total ~9.6 MB of workspace

    normalize_kernel<<<(2 * NITEM * HW + 255) / 256, 256, 0, stream>>>(f1, f2, fiN, frN, ssn);
    refnorm_kernel<<<(NITEM * NP + 255) / 256, 256, 0, stream>>>(ssn, invn);
    hipMemsetAsync(best, 0, (size_t)NITEM * NP * sizeof(unsigned long long) + 64, stream);
    corr_skew_kernel<<<NBLOCKS, 256, 0, stream>>>(fiN, frN, invn, best, tick);
    expand_best_kernel<<<(NITEM * 18 * HW + 255) / 256, 256, 0, stream>>>(best, (float*)d_out);
}

// Round 3
// 880.439 us; speedup vs baseline: 1.5820x; 1.5820x over previous
//
#include <hip/hip_runtime.h>
#include <math.h>

// Problem constants (N=2, C=64, H=96, W=96, PATCH=3)
static constexpr int NITEM = 2;
static constexpr int C = 64;
static constexpr int W = 96;
static constexpr int H = 96;
static constexpr int HW = H * W;        // 9216
static constexpr int HP = 94;           // H - 3 + 1
static constexpr int NP = HP * HP;      // 8836

// Piece decomposition: per (n, dy) split valid yi-range into 16-row pieces.
// Sum over dy of ceil(nyi/16) = 642 per item (nyi = 94-|dy|).
static constexpr int PL = 16;
static constexpr int PIECES_PER_N = 642;
static constexpr int NBLOCKS = 768;     // 3 blocks/CU x 256 CUs

// Order-preserving fp32 -> uint32 (v1 > v2  <=>  key(v1) > key(v2))
__device__ __forceinline__ unsigned int fkey(float v) {
    unsigned int u = __float_as_uint(v);
    return (u & 0x80000000u) ? ~u : (u | 0x80000000u);
}

// ---------------- Kernel 1: normalize + dual-layout repack ----------------
// fiP: per-row panel images [n][row][c2][u] float2  (linear 24576B/row -> DMA-able)
// frT: channel-pair major  [n][c2][pix]    float2  (B operand read direct from L1/L2)
__global__ __launch_bounds__(256) void normalize_kernel(
    const float* __restrict__ f1, const float* __restrict__ f2,
    float2* __restrict__ fiP, float2* __restrict__ frT, float* __restrict__ ssn)
{
    int t = blockIdx.x * 256 + threadIdx.x;
    const int perTensor = NITEM * HW;
    if (t >= 2 * perTensor) return;
    int which = t / perTensor;
    int p = t - which * perTensor;
    int n = p / HW;
    int pix = p - n * HW;
    const float* src = (which ? f2 : f1) + (size_t)n * C * HW + pix;
    float s = 0.f;
    #pragma unroll
    for (int c = 0; c < C; c++) {
        float v = src[c * HW];
        s = fmaf(v, v, s);
    }
    float norm = sqrtf(s);
    float scale = 1.0f / fmaxf(norm, 1e-12f);
    if (which) {
        float2* dst = frT + (size_t)n * 32 * HW + pix;
        #pragma unroll
        for (int c2 = 0; c2 < 32; c2++)
            dst[(size_t)c2 * HW] = make_float2(src[(2 * c2) * HW] * scale,
                                               src[(2 * c2 + 1) * HW] * scale);
        ssn[p] = s * scale * scale;
    } else {
        int y = pix / W, x = pix - y * W;
        float2* dst = fiP + ((size_t)n * H + y) * (32 * W) + x;
        #pragma unroll
        for (int c2 = 0; c2 < 32; c2++)
            dst[c2 * W] = make_float2(src[(2 * c2) * HW] * scale,
                                      src[(2 * c2 + 1) * HW] * scale);
    }
}

// ---------------- Kernel 2: ref patch inverse norms ----------------
__global__ __launch_bounds__(256) void refnorm_kernel(
    const float* __restrict__ ssn, float* __restrict__ invn)
{
    int t = blockIdx.x * 256 + threadIdx.x;
    if (t >= NITEM * NP) return;
    int n = t / NP;
    int r = t - n * NP;
    int yr = r / HP, xr = r - yr * HP;
    const float* s = ssn + n * HW;
    float acc = 0.f;
    #pragma unroll
    for (int dy = 0; dy < 3; dy++)
        #pragma unroll
        for (int dx = 0; dx < 3; dx++)
            acc += s[(yr + dy) * W + (xr + dx)];
    invn[t] = 1.0f / (sqrtf(acc) + 1e-5f);
}

// ---- async row staging: linear 24576B panel image -> LDS (per-wave quarter) ----
__device__ __forceinline__ void stage_row(const void* gsrc, void* ldst, int lane, int wv)
{
#if defined(__has_builtin) && __has_builtin(__builtin_amdgcn_global_load_lds)
    const char* g = (const char*)gsrc;
    char* l = (char*)ldst;
    #pragma unroll
    for (int c = 0; c < 6; ++c) {
        const int off = wv * 6144 + c * 1024;
        __builtin_amdgcn_global_load_lds(
            (const __attribute__((address_space(1))) unsigned int*)(const void*)(g + off + lane * 16),
            (__attribute__((address_space(3))) unsigned int*)(void*)(l + off),
            16, 0, 0);
    }
#else
    const char* g = (const char*)gsrc;
    char* l = (char*)ldst;
    #pragma unroll
    for (int c = 0; c < 6; ++c) {
        const int off = wv * 6144 + c * 1024 + lane * 16;
        *(float4*)(l + off) = *(const float4*)(g + off);
    }
#endif
}

// ---------------- Kernel 3: fused row-pair GEMM + register diagonal taps + argmax ----
// Per (n, dy, yi-piece): stream y. G_y[u][v] = dot(fi[y][u], fr[y+dy][v]) in 6x6
// register fragments (16x16 thread grid). x-taps Bx[i][j] = (G[u][v]+G[u+1][v+1])
// +G[u+2][v+2] via shfl halo; y-taps via pA/pB register rotation; finalize yi=y-2:
// (pA+Bx)*inv, argmax over xr (16-lane fmax reduce + ballot), packed-u64 atomicMax.
// A panel: double-buffered global_load_lds DMA. B operand: direct global (L1).
// Bit-identical association to the proven R0/R1 kernels.
__global__ __launch_bounds__(256, 3) void corr_fused_kernel(
    const float2* __restrict__ fiP, const float2* __restrict__ frT,
    const float* __restrict__ invn, unsigned long long* __restrict__ best,
    unsigned int* __restrict__ tick)
{
    __shared__ struct {
        float2 Ap[2][32][96];      // 49152 B: double-buffered fi-row panel image
        float  sh[2][3][2][100];   //  4800 B: halo rows for wave-boundary groups
        int    sp;
    } sm;                          // ~54.0 KB -> 3 blocks/CU (<= 54.6 KB budget)

    const int t = threadIdx.x;
    const int tu = t >> 4, tv = t & 15;     // 16x16 grid of 6x6 fragments
    const int lane = t & 63;
    const int quad = tu & 3;                // row-subgroup within wave
    const int wv = t >> 6;
    const int u0 = 6 * tu, v0 = 6 * tv;
    const unsigned long long gmask = 0xFFFFull << (lane & 48);

    const int pool = blockIdx.x & 7;        // per-XCD ticket pool (locality heuristic)
    const int n = pool >> 2;                // pools 0-3 -> item 0, 4-7 -> item 1
    const int jl = pool & 3;

    const float2* fiPn = fiP + (size_t)n * H * (32 * W);
    const float2* frTn = frT + (size_t)n * 32 * HW;
    const float* inv = invn + (size_t)n * NP;
    unsigned long long* bn = best + (size_t)n * NP;

    float pA[6][6], pB[6][6];

    for (;;) {
        if (t == 0) sm.sp = (int)atomicAdd(&tick[pool * 16], 1u);
        __syncthreads();
        const int pj = sm.sp * 4 + jl;      // piece index within item
        if (pj >= PIECES_PER_N) break;

        // ---- decode piece -> (dy, ya, nb) ----
        int dy = 0, ya = 0, nb = 0;
        {
            int r = pj;
            for (int d = 0; d < 187; ++d) {
                int a = d < 93 ? 93 - d : d - 93;
                int nyi = 94 - a;
                int q = (nyi + PL - 1) / PL;
                if (r < q) {
                    dy = d - 93;
                    ya = (dy < 0 ? -dy : 0) + r * PL;
                    nb = nyi - r * PL; if (nb > PL) nb = PL;
                    break;
                }
                r -= q;
            }
        }
        const int yb = ya + nb;             // finalize yi in [ya, yb); y runs ya..yb+1

        // prologue: DMA row ya into buffer 0
        stage_row(fiPn + (size_t)ya * (32 * W), &sm.Ap[0][0][0], lane, wv);
        asm volatile("s_waitcnt vmcnt(0)" ::: "memory");
        __syncthreads();

        for (int y = ya; y <= yb + 1; ++y) {
            const int idx = (y - ya) & 1;
            const bool doLd = (y <= yb);
            const bool doFin = (y >= ya + 2);
            const bool doA = (y > ya);
            const int yi = y - 2;
            const int yr = yi + dy;

            // issue next-row DMA first: latency hides under the whole GEMM
            if (doLd)
                stage_row(fiPn + (size_t)(y + 1) * (32 * W), &sm.Ap[idx ^ 1][0][0], lane, wv);

            float ivr[6];
            if (doFin) {
                const float* ivp = inv + (size_t)yr * HP;
                #pragma unroll
                for (int jj = 0; jj < 6; ++jj) {
                    int xr = v0 + jj;
                    ivr[jj] = ivp[xr > 93 ? 93 : xr];   // clamp; garbage masked later
                }
            }

            // ---- GEMM: A from LDS panel, B direct from global (L1-resident row) ----
            float acc[6][6];
            #pragma unroll
            for (int i = 0; i < 6; ++i)
                #pragma unroll
                for (int jj = 0; jj < 6; ++jj) acc[i][jj] = 0.f;

            const int pixB = (y + dy) * W;
            #pragma unroll 2
            for (int kp = 0; kp < 32; ++kp) {
                const float4* ap = (const float4*)&sm.Ap[idx][kp][u0];
                const float4* bp = (const float4*)(frTn + (size_t)kp * HW + pixB + v0);
                float4 a01 = ap[0], a23 = ap[1], a45 = ap[2];
                float4 b01 = bp[0], b23 = bp[1], b45 = bp[2];
                float ae[6] = {a01.x, a01.z, a23.x, a23.z, a45.x, a45.z};
                float ao[6] = {a01.y, a01.w, a23.y, a23.w, a45.y, a45.w};
                float be[6] = {b01.x, b01.z, b23.x, b23.z, b45.x, b45.z};
                float bo[6] = {b01.y, b01.w, b23.y, b23.w, b45.y, b45.w};
                #pragma unroll
                for (int i = 0; i < 6; ++i)
                    #pragma unroll
                    for (int jj = 0; jj < 6; ++jj) {
                        acc[i][jj] = fmaf(ae[i], be[jj], acc[i][jj]);  // even ch then
                        acc[i][jj] = fmaf(ao[i], bo[jj], acc[i][jj]);  // odd: asc-c chain
                    }
            }

            // publish halo rows 0,1 for wave-boundary consumers (tu in {3,7,11})
            if (quad == 0 && tu >= 4) {
                const int g = (tu >> 2) - 1;
                #pragma unroll
                for (int jj = 0; jj < 6; ++jj) {
                    sm.sh[idx][g][0][v0 + jj] = acc[0][jj];
                    sm.sh[idx][g][1][v0 + jj] = acc[1][jj];
                }
            }

            asm volatile("s_waitcnt vmcnt(0)" ::: "memory");  // my DMA quarter done
            __syncthreads();   // single barrier: halo visible + all DMA complete

            // ---- neighbor exchange (uniform shfls; select after) ----
            float c6[6], c7[6];
            #pragma unroll
            for (int i = 0; i < 6; ++i) {
                c6[i] = __shfl_down(acc[i][0], 1);   // col u0+i, v0+6
                c7[i] = __shfl_down(acc[i][1], 1);   // col u0+i, v0+7
            }
            float e6[8], e7[8];
            #pragma unroll
            for (int jj = 0; jj < 6; ++jj) {
                e6[jj] = __shfl_down(acc[0][jj], 16);  // row u0+6
                e7[jj] = __shfl_down(acc[1][jj], 16);  // row u0+7
            }
            e6[6] = __shfl_down(acc[0][0], 17);
            e6[7] = __shfl_down(acc[0][1], 17);
            e7[6] = __shfl_down(acc[1][0], 17);
            e7[7] = __shfl_down(acc[1][1], 17);
            if (quad == 3) {
                if (tu < 15) {
                    const int g = tu >> 2;
                    #pragma unroll
                    for (int jj = 0; jj < 8; ++jj) {
                        e6[jj] = sm.sh[idx][g][0][v0 + jj];
                        e7[jj] = sm.sh[idx][g][1][v0 + jj];
                    }
                } else {
                    #pragma unroll
                    for (int jj = 0; jj < 8; ++jj) { e6[jj] = 0.f; e7[jj] = 0.f; }
                }
            }

            // ---- diagonal x-taps + y-rotation + finalize yi = y-2 ----
            #pragma unroll
            for (int i = 0; i < 6; ++i) {
                float bv = -INFINITY; int bxr = 0;
                #pragma unroll
                for (int jj = 0; jj < 6; ++jj) {
                    const int i1 = (i + 1 <= 5) ? i + 1 : 0;
                    const int j1 = (jj + 1 <= 5) ? jj + 1 : 0;
                    const int i2 = (i + 2 <= 5) ? i + 2 : 0;
                    const int j2 = (jj + 2 <= 5) ? jj + 2 : 0;
                    float E0 = acc[i][jj];
                    float E1 = (i + 1 <= 5)
                             ? ((jj + 1 <= 5) ? acc[i1][j1] : c6[i1])
                             : e6[jj + 1];
                    float E2 = (i + 2 <= 5)
                             ? ((jj + 2 <= 5) ? acc[i2][j2]
                                              : ((jj + 2 == 6) ? c6[i2] : c7[i2]))
                             : ((i + 2 == 6) ? e6[jj + 2] : e7[jj + 2]);
                    float bx = (E0 + E1) + E2;           // (g0+g1)+g2, as pass2
                    if (doFin) {
                        float v = (pA[i][jj] + bx) * ivr[jj];  // ((B0+B1)+B2)*inv
                        int xr = v0 + jj;
                        if (xr < HP && (u0 + i) < HP && v > bv) { bv = v; bxr = xr; }
                    }
                    if (doA) pA[i][jj] = pB[i][jj] + bx;
                    pB[i][jj] = bx;
                }
                if (doFin) {
                    float mx = bv;
                    #pragma unroll
                    for (int m = 1; m < 16; m <<= 1)
                        mx = fmaxf(mx, __shfl_xor(mx, m));   // 16-lane xr-group max
                    unsigned long long ball = __ballot(bv == mx) & gmask;
                    int srcl = __ffsll(ball) - 1;            // lowest lane = min xr
                    int wxr = __shfl(bxr, srcl);
                    if (tv == 0 && (u0 + i) < HP) {
                        unsigned long long key =
                            ((unsigned long long)fkey(mx) << 32)
                          | (unsigned int)(~(unsigned int)(yr * HP + wxr));
                        atomicMax(&bn[(size_t)yi * HP + (u0 + i)], key);
                    }
                }
            }
        }
    }
}

// ---------------- Kernel 4: expand to 9 shifted copies, channel-interleaved ----------------
__global__ __launch_bounds__(256) void expand_best_kernel(
    const unsigned long long* __restrict__ best, float* __restrict__ out)
{
    int t = blockIdx.x * 256 + threadIdx.x;
    const int total = NITEM * 18 * HW;
    if (t >= total) return;
    int x = t % W;
    int y = (t / W) % H;
    int chn = (t / HW) % 18;
    int n = t / (18 * HW);
    int k = chn >> 1;
    int b = chn & 1;          // 0 -> flow_h, 1 -> flow_w
    int is = k / 3, js = k - is * 3;
    int ys = y - is, xs = x - js;
    float val = 0.f;
    if (ys >= 0 && ys < HP && xs >= 0 && xs < HP) {
        int i = ys * HP + xs;
        unsigned long long key = best[(size_t)n * NP + i];
        int idx = (int)(~(unsigned int)key);
        int yr = idx / HP, xr = idx - yr * HP;
        val = b ? (float)(xr - xs) : (float)(yr - ys);
    }
    out[t] = val;
}

// ---------------- Launch ----------------
extern "C" void kernel_launch(void* const* d_in, const int* in_sizes, int n_in,
                              void* d_out, int out_size, void* d_ws, size_t ws_size,
                              hipStream_t stream) {
    (void)in_sizes; (void)n_in; (void)out_size; (void)ws_size;
    const float* f1 = (const float*)d_in[0];
    const float* f2 = (const float*)d_in[1];

    float2* fiP = (float2*)d_ws;                            // 2*96*32*96 float2 = 4.7 MB
    float2* frT = fiP + (size_t)NITEM * H * 32 * W;         // 4.7 MB
    float*  ssn = (float*)(frT + (size_t)NITEM * 32 * HW);  // 2*9216
    float*  invn = ssn + (size_t)NITEM * HW;                // 2*8836
    unsigned long long* best =
        (unsigned long long*)((((uintptr_t)(invn + (size_t)NITEM * NP)) + 63) & ~(uintptr_t)63);
    unsigned int* tick = (unsigned int*)(best + (size_t)NITEM * NP);  // 8 pools, 64B apart
    // total ~9.7 MB of workspace

    normalize_kernel<<<(2 * NITEM * HW + 255) / 256, 256, 0, stream>>>(f1, f2, fiP, frT, ssn);
    refnorm_kernel<<<(NITEM * NP + 255) / 256, 256, 0, stream>>>(ssn, invn);
    hipMemsetAsync(best, 0, (size_t)NITEM * NP * sizeof(unsigned long long) + 512, stream);
    corr_fused_kernel<<<NBLOCKS, 256, 0, stream>>>(fiP, frT, invn, best, tick);
    expand_best_kernel<<<(NITEM * 18 * HW + 255) / 256, 256, 0, stream>>>(best, (float*)d_out);
}

// Round 4
// 661.511 us; speedup vs baseline: 2.1055x; 1.3310x over previous
//
#include <hip/hip_runtime.h>
#include <math.h>

// Problem constants (N=2, C=64, H=96, W=96, PATCH=3)
static constexpr int NITEM = 2;
static constexpr int C = 64;
static constexpr int W = 96;
static constexpr int H = 96;
static constexpr int HW = H * W;        // 9216
static constexpr int HP = 94;           // H - 3 + 1
static constexpr int NP = HP * HP;      // 8836

// Piece decomposition: per (n, dy) split valid yi-range into 16-row pieces.
// Sum over dy of ceil(nyi/16) = 642 per item (nyi = 94-|dy|).
static constexpr int PL = 16;
static constexpr int PIECES_PER_N = 642;
static constexpr int NBLOCKS = 768;

// Order-preserving fp32 -> uint32 (v1 > v2  <=>  key(v1) > key(v2))
__device__ __forceinline__ unsigned int fkey(float v) {
    unsigned int u = __float_as_uint(v);
    return (u & 0x80000000u) ? ~u : (u | 0x80000000u);
}

// ---------------- Kernel 1: normalize + per-row panel repack ----------------
// fiP/frP: per-row panel images [n][row][c2][x] float2 (linear 24576B/row -> DMA-able)
__global__ __launch_bounds__(256) void normalize_kernel(
    const float* __restrict__ f1, const float* __restrict__ f2,
    float2* __restrict__ fiP, float2* __restrict__ frP, float* __restrict__ ssn)
{
    int t = blockIdx.x * 256 + threadIdx.x;
    const int perTensor = NITEM * HW;
    if (t >= 2 * perTensor) return;
    int which = t / perTensor;
    int p = t - which * perTensor;
    int n = p / HW;
    int pix = p - n * HW;
    const float* src = (which ? f2 : f1) + (size_t)n * C * HW + pix;
    float s = 0.f;
    #pragma unroll
    for (int c = 0; c < C; c++) {
        float v = src[c * HW];
        s = fmaf(v, v, s);
    }
    float norm = sqrtf(s);
    float scale = 1.0f / fmaxf(norm, 1e-12f);
    int y = pix / W, x = pix - y * W;
    float2* base = (which ? frP : fiP) + ((size_t)n * H + y) * (32 * W) + x;
    #pragma unroll
    for (int c2 = 0; c2 < 32; c2++)
        base[c2 * W] = make_float2(src[(2 * c2) * HW] * scale,
                                   src[(2 * c2 + 1) * HW] * scale);
    if (which) ssn[p] = s * scale * scale;
}

// ---------------- Kernel 2: ref patch inverse norms ----------------
__global__ __launch_bounds__(256) void refnorm_kernel(
    const float* __restrict__ ssn, float* __restrict__ invn)
{
    int t = blockIdx.x * 256 + threadIdx.x;
    if (t >= NITEM * NP) return;
    int n = t / NP;
    int r = t - n * NP;
    int yr = r / HP, xr = r - yr * HP;
    const float* s = ssn + n * HW;
    float acc = 0.f;
    #pragma unroll
    for (int dy = 0; dy < 3; dy++)
        #pragma unroll
        for (int dx = 0; dx < 3; dx++)
            acc += s[(yr + dy) * W + (xr + dx)];
    invn[t] = 1.0f / (sqrtf(acc) + 1e-5f);
}

// ---- async row staging: linear 24576B panel image -> LDS (per-wave quarter) ----
__device__ __forceinline__ void stage_row(const void* gsrc, void* ldst, int lane, int wv)
{
#if defined(__has_builtin) && __has_builtin(__builtin_amdgcn_global_load_lds)
    const char* g = (const char*)gsrc;
    char* l = (char*)ldst;
    #pragma unroll
    for (int c = 0; c < 6; ++c) {
        const int off = wv * 6144 + c * 1024;
        __builtin_amdgcn_global_load_lds(
            (const __attribute__((address_space(1))) unsigned int*)(const void*)(g + off + lane * 16),
            (__attribute__((address_space(3))) unsigned int*)(void*)(l + off),
            16, 0, 0);
    }
#else
    const char* g = (const char*)gsrc;
    char* l = (char*)ldst;
    #pragma unroll
    for (int c = 0; c < 6; ++c) {
        const int off = wv * 6144 + c * 1024 + lane * 16;
        *(float4*)(l + off) = *(const float4*)(g + off);
    }
#endif
}

// ---------------- Kernel 3: fused row-pair GEMM + register diagonal taps + argmax ----
// Per (n, dy, yi-piece): stream y. G_y[u][v] = dot(fi[y][u], fr[y+dy][v]) in 6x6
// register fragments (16x16 thread grid), BOTH operands from single-buffered LDS
// panels (24KB each) staged by global_load_lds DMA. Per step:
//   GEMM -> halo publish -> barrier1 -> issue next-row DMA (A and B)
//        -> shfl halo exchange + x-taps + y-rotation + finalize -> vmcnt(0) -> barrier2.
// pA/pB rotation state lives in REGISTERS; __launch_bounds__(256,2) gives a 256-VGPR
// budget so nothing spills (R3's 84-VGPR spill disaster is the bug being fixed).
// atomicMax is guarded by a plain read (values grow monotonically -> stale-read skip
// is safe), removing ~97% of the 1.7M device-scope atomics.
// Bit-identical association to the proven R0-R3 kernels: ascending-c fmaf chain,
// (g0+g1)+g2 over dx, ((B0+B1)+B2)*inv over dy, fkey/~idx tie-break.
__global__ __launch_bounds__(256, 2) void corr_fused_kernel(
    const float2* __restrict__ fiP, const float2* __restrict__ frP,
    const float* __restrict__ invn, unsigned long long* __restrict__ best,
    unsigned int* __restrict__ tick)
{
    __shared__ struct {
        float2 Ap[32][96];      // 24576 B: fi-row panel (single-buffered)
        float2 Bp[32][96];      // 24576 B: fr-row panel (single-buffered)
        float  sh[3][2][100];   //  2400 B: halo rows for wave-boundary groups
        int    sp;
    } sm;                       // ~51.6 KB

    const int t = threadIdx.x;
    const int tu = t >> 4, tv = t & 15;     // 16x16 grid of 6x6 fragments
    const int lane = t & 63;
    const int quad = tu & 3;                // row-subgroup within wave
    const int wv = t >> 6;
    const int u0 = 6 * tu, v0 = 6 * tv;
    const unsigned long long gmask = 0xFFFFull << (lane & 48);

    const int pool = blockIdx.x & 7;        // per-XCD ticket pool (locality heuristic)
    const int n = pool >> 2;                // pools 0-3 -> item 0, 4-7 -> item 1
    const int jl = pool & 3;

    const float2* fiPn = fiP + (size_t)n * H * (32 * W);
    const float2* frPn = frP + (size_t)n * H * (32 * W);
    const float* inv = invn + (size_t)n * NP;
    unsigned long long* bn = best + (size_t)n * NP;

    float pA[6][6], pB[6][6];

    for (;;) {
        if (t == 0) sm.sp = (int)atomicAdd(&tick[pool * 16], 1u);
        __syncthreads();
        const int pj = sm.sp * 4 + jl;      // piece index within item
        if (pj >= PIECES_PER_N) break;

        // ---- decode piece -> (dy, ya, nb) ----
        int dy = 0, ya = 0, nb = 0;
        {
            int r = pj;
            for (int d = 0; d < 187; ++d) {
                int a = d < 93 ? 93 - d : d - 93;
                int nyi = 94 - a;
                int q = (nyi + PL - 1) / PL;
                if (r < q) {
                    dy = d - 93;
                    ya = (dy < 0 ? -dy : 0) + r * PL;
                    nb = nyi - r * PL; if (nb > PL) nb = PL;
                    break;
                }
                r -= q;
            }
        }
        const int yb = ya + nb;             // finalize yi in [ya, yb); y runs ya..yb+1

        // prologue: DMA rows (ya, ya+dy)
        stage_row(fiPn + (size_t)ya * (32 * W), &sm.Ap[0][0], lane, wv);
        stage_row(frPn + (size_t)(ya + dy) * (32 * W), &sm.Bp[0][0], lane, wv);
        asm volatile("s_waitcnt vmcnt(0)" ::: "memory");
        __syncthreads();

        for (int y = ya; y <= yb + 1; ++y) {
            const bool doLd = (y <= yb);
            const bool doFin = (y >= ya + 2);
            const bool doA = (y > ya);
            const int yi = y - 2;
            const int yr = yi + dy;

            // ---- GEMM: A and B from LDS panels ----
            float acc[6][6];
            #pragma unroll
            for (int i = 0; i < 6; ++i)
                #pragma unroll
                for (int jj = 0; jj < 6; ++jj) acc[i][jj] = 0.f;

            #pragma unroll 2
            for (int kp = 0; kp < 32; ++kp) {
                const float4* ap = (const float4*)&sm.Ap[kp][u0];
                const float4* bp = (const float4*)&sm.Bp[kp][v0];
                float4 a01 = ap[0], a23 = ap[1], a45 = ap[2];
                float4 b01 = bp[0], b23 = bp[1], b45 = bp[2];
                float ae[6] = {a01.x, a01.z, a23.x, a23.z, a45.x, a45.z};
                float ao[6] = {a01.y, a01.w, a23.y, a23.w, a45.y, a45.w};
                float be[6] = {b01.x, b01.z, b23.x, b23.z, b45.x, b45.z};
                float bo[6] = {b01.y, b01.w, b23.y, b23.w, b45.y, b45.w};
                #pragma unroll
                for (int i = 0; i < 6; ++i)
                    #pragma unroll
                    for (int jj = 0; jj < 6; ++jj) {
                        acc[i][jj] = fmaf(ae[i], be[jj], acc[i][jj]);  // even ch then
                        acc[i][jj] = fmaf(ao[i], bo[jj], acc[i][jj]);  // odd: asc-c chain
                    }
            }

            // publish halo rows 0,1 for wave-boundary consumers (tu in {3,7,11})
            if (quad == 0 && tu >= 4) {
                const int g = (tu >> 2) - 1;
                #pragma unroll
                for (int jj = 0; jj < 6; ++jj) {
                    sm.sh[g][0][v0 + jj] = acc[0][jj];
                    sm.sh[g][1][v0 + jj] = acc[1][jj];
                }
            }
            __syncthreads();   // barrier1: GEMM panel reads done + halo visible

            // issue next-row DMA; latency hides under taps/finalize
            if (doLd) {
                stage_row(fiPn + (size_t)(y + 1) * (32 * W), &sm.Ap[0][0], lane, wv);
                stage_row(frPn + (size_t)(y + 1 + dy) * (32 * W), &sm.Bp[0][0], lane, wv);
            }

            // ---- neighbor exchange (uniform shfls; select after) ----
            float c6[6], c7[6];
            #pragma unroll
            for (int i = 0; i < 6; ++i) {
                c6[i] = __shfl_down(acc[i][0], 1);   // col u0+i, v0+6
                c7[i] = __shfl_down(acc[i][1], 1);   // col u0+i, v0+7
            }
            float e6[8], e7[8];
            #pragma unroll
            for (int jj = 0; jj < 6; ++jj) {
                e6[jj] = __shfl_down(acc[0][jj], 16);  // row u0+6
                e7[jj] = __shfl_down(acc[1][jj], 16);  // row u0+7
            }
            e6[6] = __shfl_down(acc[0][0], 17);
            e6[7] = __shfl_down(acc[0][1], 17);
            e7[6] = __shfl_down(acc[1][0], 17);
            e7[7] = __shfl_down(acc[1][1], 17);
            if (quad == 3) {
                if (tu < 15) {
                    const int g = tu >> 2;
                    #pragma unroll
                    for (int jj = 0; jj < 8; ++jj) {
                        e6[jj] = sm.sh[g][0][v0 + jj];
                        e7[jj] = sm.sh[g][1][v0 + jj];
                    }
                } else {
                    #pragma unroll
                    for (int jj = 0; jj < 8; ++jj) { e6[jj] = 0.f; e7[jj] = 0.f; }
                }
            }

            float ivr[6];
            if (doFin) {
                const float* ivp = inv + (size_t)yr * HP;
                #pragma unroll
                for (int jj = 0; jj < 6; ++jj) {
                    int xr = v0 + jj;
                    ivr[jj] = ivp[xr > 93 ? 93 : xr];   // clamp; garbage masked later
                }
            }

            // ---- diagonal x-taps + y-rotation + finalize yi = y-2 ----
            #pragma unroll
            for (int i = 0; i < 6; ++i) {
                float bv = -INFINITY; int bxr = 0;
                #pragma unroll
                for (int jj = 0; jj < 6; ++jj) {
                    const int i1 = (i + 1 <= 5) ? i + 1 : 0;
                    const int j1 = (jj + 1 <= 5) ? jj + 1 : 0;
                    const int i2 = (i + 2 <= 5) ? i + 2 : 0;
                    const int j2 = (jj + 2 <= 5) ? jj + 2 : 0;
                    float E0 = acc[i][jj];
                    float E1 = (i + 1 <= 5)
                             ? ((jj + 1 <= 5) ? acc[i1][j1] : c6[i1])
                             : e6[jj + 1];
                    float E2 = (i + 2 <= 5)
                             ? ((jj + 2 <= 5) ? acc[i2][j2]
                                              : ((jj + 2 == 6) ? c6[i2] : c7[i2]))
                             : ((i + 2 == 6) ? e6[jj + 2] : e7[jj + 2]);
                    float bx = (E0 + E1) + E2;           // (g0+g1)+g2, as pass2
                    if (doFin) {
                        float v = (pA[i][jj] + bx) * ivr[jj];  // ((B0+B1)+B2)*inv
                        int xr = v0 + jj;
                        if (xr < HP && (u0 + i) < HP && v > bv) { bv = v; bxr = xr; }
                    }
                    if (doA) pA[i][jj] = pB[i][jj] + bx;
                    pB[i][jj] = bx;
                }
                if (doFin) {
                    float mx = bv;
                    #pragma unroll
                    for (int m = 1; m < 16; m <<= 1)
                        mx = fmaxf(mx, __shfl_xor(mx, m));   // 16-lane xr-group max
                    unsigned long long ball = __ballot(bv == mx) & gmask;
                    int srcl = __ffsll(ball) - 1;            // lowest lane = min xr
                    int wxr = __shfl(bxr, srcl);
                    if (tv == 0 && (u0 + i) < HP) {
                        unsigned long long key =
                            ((unsigned long long)fkey(mx) << 32)
                          | (unsigned int)(~(unsigned int)(yr * HP + wxr));
                        const size_t off = (size_t)yi * HP + (u0 + i);
                        if (key > bn[off]) atomicMax(&bn[off], key);  // monotone: stale-skip safe
                    }
                }
            }

            if (doLd) asm volatile("s_waitcnt vmcnt(0)" ::: "memory");
            __syncthreads();   // barrier2: next panels staged in all quarters
        }
    }
}

// ---------------- Kernel 4: expand to 9 shifted copies, channel-interleaved ----------------
__global__ __launch_bounds__(256) void expand_best_kernel(
    const unsigned long long* __restrict__ best, float* __restrict__ out)
{
    int t = blockIdx.x * 256 + threadIdx.x;
    const int total = NITEM * 18 * HW;
    if (t >= total) return;
    int x = t % W;
    int y = (t / W) % H;
    int chn = (t / HW) % 18;
    int n = t / (18 * HW);
    int k = chn >> 1;
    int b = chn & 1;          // 0 -> flow_h, 1 -> flow_w
    int is = k / 3, js = k - is * 3;
    int ys = y - is, xs = x - js;
    float val = 0.f;
    if (ys >= 0 && ys < HP && xs >= 0 && xs < HP) {
        int i = ys * HP + xs;
        unsigned long long key = best[(size_t)n * NP + i];
        int idx = (int)(~(unsigned int)key);
        int yr = idx / HP, xr = idx - yr * HP;
        val = b ? (float)(xr - xs) : (float)(yr - ys);
    }
    out[t] = val;
}

// ---------------- Launch ----------------
extern "C" void kernel_launch(void* const* d_in, const int* in_sizes, int n_in,
                              void* d_out, int out_size, void* d_ws, size_t ws_size,
                              hipStream_t stream) {
    (void)in_sizes; (void)n_in; (void)out_size; (void)ws_size;
    const float* f1 = (const float*)d_in[0];
    const float* f2 = (const float*)d_in[1];

    float2* fiP = (float2*)d_ws;                            // 2*96*32*96 float2 = 4.7 MB
    float2* frP = fiP + (size_t)NITEM * H * 32 * W;         // 4.7 MB
    float*  ssn = (float*)(frP + (size_t)NITEM * H * 32 * W);
    float*  invn = ssn + (size_t)NITEM * HW;
    unsigned long long* best =
        (unsigned long long*)((((uintptr_t)(invn + (size_t)NITEM * NP)) + 63) & ~(uintptr_t)63);
    unsigned int* tick = (unsigned int*)(best + (size_t)NITEM * NP);  // 8 pools, 64B apart
    // total ~9.7 MB of workspace

    normalize_kernel<<<(2 * NITEM * HW + 255) / 256, 256, 0, stream>>>(f1, f2, fiP, frP, ssn);
    refnorm_kernel<<<(NITEM * NP + 255) / 256, 256, 0, stream>>>(ssn, invn);
    hipMemsetAsync(best, 0, (size_t)NITEM * NP * sizeof(unsigned long long) + 512, stream);
    corr_fused_kernel<<<NBLOCKS, 256, 0, stream>>>(fiP, frP, invn, best, tick);
    expand_best_kernel<<<(NITEM * 18 * HW + 255) / 256, 256, 0, stream>>>(best, (float*)d_out);
}

// Round 5
// 613.441 us; speedup vs baseline: 2.2705x; 1.0784x over previous
//
#include <hip/hip_runtime.h>
#include <math.h>

// Problem constants (N=2, C=64, H=96, W=96, PATCH=3)
static constexpr int NITEM = 2;
static constexpr int C = 64;
static constexpr int W = 96;
static constexpr int H = 96;
static constexpr int HW = H * W;        // 9216
static constexpr int HP = 94;           // H - 3 + 1
static constexpr int NP = HP * HP;      // 8836

// Work units: per (n, dy) split the valid yi-range into PL-row pieces.
// PL=8: units/item = ceil(94/8) + 2*sum_{a=1..93} ceil((94-a)/8) = 12 + 2*588 = 1188.
// 384 blocks/item -> 3.09 units/block; center-out dy order puts the fractional
// edge-|dy| pieces at the tail of the ticket sequence (drain-filler, not straggler).
static constexpr int PL = 8;
static constexpr int UNITS_PER_N = 1188;
static constexpr int NBLOCKS = 768;     // 3 blocks/CU x 256 CUs

// Order-preserving fp32 -> uint32 (v1 > v2  <=>  key(v1) > key(v2))
__device__ __forceinline__ unsigned int fkey(float v) {
    unsigned int u = __float_as_uint(v);
    return (u & 0x80000000u) ? ~u : (u | 0x80000000u);
}

// ---------------- Kernel 1: normalize + per-row panel repack ----------------
// fiP/frP: per-row panel images [n][row][c2][x] float2 (linear 24576B/row -> DMA-able)
__global__ __launch_bounds__(256) void normalize_kernel(
    const float* __restrict__ f1, const float* __restrict__ f2,
    float2* __restrict__ fiP, float2* __restrict__ frP, float* __restrict__ ssn)
{
    int t = blockIdx.x * 256 + threadIdx.x;
    const int perTensor = NITEM * HW;
    if (t >= 2 * perTensor) return;
    int which = t / perTensor;
    int p = t - which * perTensor;
    int n = p / HW;
    int pix = p - n * HW;
    const float* src = (which ? f2 : f1) + (size_t)n * C * HW + pix;
    float s = 0.f;
    #pragma unroll
    for (int c = 0; c < C; c++) {
        float v = src[c * HW];
        s = fmaf(v, v, s);
    }
    float norm = sqrtf(s);
    float scale = 1.0f / fmaxf(norm, 1e-12f);
    int y = pix / W, x = pix - y * W;
    float2* base = (which ? frP : fiP) + ((size_t)n * H + y) * (32 * W) + x;
    #pragma unroll
    for (int c2 = 0; c2 < 32; c2++)
        base[c2 * W] = make_float2(src[(2 * c2) * HW] * scale,
                                   src[(2 * c2 + 1) * HW] * scale);
    if (which) ssn[p] = s * scale * scale;
}

// ---------------- Kernel 2: ref patch inverse norms ----------------
__global__ __launch_bounds__(256) void refnorm_kernel(
    const float* __restrict__ ssn, float* __restrict__ invn)
{
    int t = blockIdx.x * 256 + threadIdx.x;
    if (t >= NITEM * NP) return;
    int n = t / NP;
    int r = t - n * NP;
    int yr = r / HP, xr = r - yr * HP;
    const float* s = ssn + n * HW;
    float acc = 0.f;
    #pragma unroll
    for (int dy = 0; dy < 3; dy++)
        #pragma unroll
        for (int dx = 0; dx < 3; dx++)
            acc += s[(yr + dy) * W + (xr + dx)];
    invn[t] = 1.0f / (sqrtf(acc) + 1e-5f);
}

// ---- async row staging: linear 24576B panel image -> LDS (per-wave quarter) ----
__device__ __forceinline__ void stage_row(const void* gsrc, void* ldst, int lane, int wv)
{
#if defined(__has_builtin) && __has_builtin(__builtin_amdgcn_global_load_lds)
    const char* g = (const char*)gsrc;
    char* l = (char*)ldst;
    #pragma unroll
    for (int c = 0; c < 6; ++c) {
        const int off = wv * 6144 + c * 1024;
        __builtin_amdgcn_global_load_lds(
            (const __attribute__((address_space(1))) unsigned int*)(const void*)(g + off + lane * 16),
            (__attribute__((address_space(3))) unsigned int*)(void*)(l + off),
            16, 0, 0);
    }
#else
    const char* g = (const char*)gsrc;
    char* l = (char*)ldst;
    #pragma unroll
    for (int c = 0; c < 6; ++c) {
        const int off = wv * 6144 + c * 1024 + lane * 16;
        *(float4*)(l + off) = *(const float4*)(g + off);
    }
#endif
}

// ---------------- Kernel 3: fused row-pair GEMM + register diagonal taps + argmax ----
// Identical math/structure to the passing R4 kernel; only the SCHEDULE changed:
// one ticket pool per item (384 blocks each), PL=8 units, center-out dy ordering.
__global__ __launch_bounds__(256, 2) void corr_fused_kernel(
    const float2* __restrict__ fiP, const float2* __restrict__ frP,
    const float* __restrict__ invn, unsigned long long* __restrict__ best,
    unsigned int* __restrict__ tick)
{
    __shared__ struct {
        float2 Ap[32][96];      // 24576 B: fi-row panel (single-buffered)
        float2 Bp[32][96];      // 24576 B: fr-row panel (single-buffered)
        float  sh[3][2][100];   //  2400 B: halo rows for wave-boundary groups
        int    sp;
    } sm;                       // ~51.6 KB -> 3 blocks/CU

    const int t = threadIdx.x;
    const int tu = t >> 4, tv = t & 15;     // 16x16 grid of 6x6 fragments
    const int lane = t & 63;
    const int quad = tu & 3;                // row-subgroup within wave
    const int wv = t >> 6;
    const int u0 = 6 * tu, v0 = 6 * tv;
    const unsigned long long gmask = 0xFFFFull << (lane & 48);

    const int n = blockIdx.x & 1;           // 384 blocks per item, XCD-interleaved

    const float2* fiPn = fiP + (size_t)n * H * (32 * W);
    const float2* frPn = frP + (size_t)n * H * (32 * W);
    const float* inv = invn + (size_t)n * NP;
    unsigned long long* bn = best + (size_t)n * NP;

    float pA[6][6], pB[6][6];

    for (;;) {
        if (t == 0) sm.sp = (int)atomicAdd(&tick[n * 16], 1u);
        __syncthreads();
        const int uj = sm.sp;               // unit index within item
        if (uj >= UNITS_PER_N) break;

        // ---- decode unit -> (dy, ya, nb), center-out dy order ----
        int dy = 0, ya = 0, nb = 0;
        {
            int r = uj;
            for (int s = 0; s < 187; ++s) {
                int ady = (s + 1) >> 1;          // 0,1,1,2,2,...,93,93
                int nyi = 94 - ady;
                int q = (nyi + PL - 1) / PL;
                if (r < q) {
                    dy = (s & 1) ? -ady : ady;
                    ya = (dy < 0 ? -dy : 0) + r * PL;
                    nb = nyi - r * PL; if (nb > PL) nb = PL;
                    break;
                }
                r -= q;
            }
        }
        const int yb = ya + nb;             // finalize yi in [ya, yb); y runs ya..yb+1

        // prologue: DMA rows (ya, ya+dy)
        stage_row(fiPn + (size_t)ya * (32 * W), &sm.Ap[0][0], lane, wv);
        stage_row(frPn + (size_t)(ya + dy) * (32 * W), &sm.Bp[0][0], lane, wv);
        asm volatile("s_waitcnt vmcnt(0)" ::: "memory");
        __syncthreads();

        for (int y = ya; y <= yb + 1; ++y) {
            const bool doLd = (y <= yb);
            const bool doFin = (y >= ya + 2);
            const bool doA = (y > ya);
            const int yi = y - 2;
            const int yr = yi + dy;

            // ---- GEMM: A and B from LDS panels ----
            float acc[6][6];
            #pragma unroll
            for (int i = 0; i < 6; ++i)
                #pragma unroll
                for (int jj = 0; jj < 6; ++jj) acc[i][jj] = 0.f;

            #pragma unroll 2
            for (int kp = 0; kp < 32; ++kp) {
                const float4* ap = (const float4*)&sm.Ap[kp][u0];
                const float4* bp = (const float4*)&sm.Bp[kp][v0];
                float4 a01 = ap[0], a23 = ap[1], a45 = ap[2];
                float4 b01 = bp[0], b23 = bp[1], b45 = bp[2];
                float ae[6] = {a01.x, a01.z, a23.x, a23.z, a45.x, a45.z};
                float ao[6] = {a01.y, a01.w, a23.y, a23.w, a45.y, a45.w};
                float be[6] = {b01.x, b01.z, b23.x, b23.z, b45.x, b45.z};
                float bo[6] = {b01.y, b01.w, b23.y, b23.w, b45.y, b45.w};
                #pragma unroll
                for (int i = 0; i < 6; ++i)
                    #pragma unroll
                    for (int jj = 0; jj < 6; ++jj) {
                        acc[i][jj] = fmaf(ae[i], be[jj], acc[i][jj]);  // even ch then
                        acc[i][jj] = fmaf(ao[i], bo[jj], acc[i][jj]);  // odd: asc-c chain
                    }
            }

            // publish halo rows 0,1 for wave-boundary consumers (tu in {3,7,11})
            if (quad == 0 && tu >= 4) {
                const int g = (tu >> 2) - 1;
                #pragma unroll
                for (int jj = 0; jj < 6; ++jj) {
                    sm.sh[g][0][v0 + jj] = acc[0][jj];
                    sm.sh[g][1][v0 + jj] = acc[1][jj];
                }
            }
            __syncthreads();   // barrier1: GEMM panel reads done + halo visible

            // issue next-row DMA; latency hides under taps/finalize
            if (doLd) {
                stage_row(fiPn + (size_t)(y + 1) * (32 * W), &sm.Ap[0][0], lane, wv);
                stage_row(frPn + (size_t)(y + 1 + dy) * (32 * W), &sm.Bp[0][0], lane, wv);
            }

            // ---- neighbor exchange (uniform shfls; select after) ----
            float c6[6], c7[6];
            #pragma unroll
            for (int i = 0; i < 6; ++i) {
                c6[i] = __shfl_down(acc[i][0], 1);   // col u0+i, v0+6
                c7[i] = __shfl_down(acc[i][1], 1);   // col u0+i, v0+7
            }
            float e6[8], e7[8];
            #pragma unroll
            for (int jj = 0; jj < 6; ++jj) {
                e6[jj] = __shfl_down(acc[0][jj], 16);  // row u0+6
                e7[jj] = __shfl_down(acc[1][jj], 16);  // row u0+7
            }
            e6[6] = __shfl_down(acc[0][0], 17);
            e6[7] = __shfl_down(acc[0][1], 17);
            e7[6] = __shfl_down(acc[1][0], 17);
            e7[7] = __shfl_down(acc[1][1], 17);
            if (quad == 3) {
                if (tu < 15) {
                    const int g = tu >> 2;
                    #pragma unroll
                    for (int jj = 0; jj < 8; ++jj) {
                        e6[jj] = sm.sh[g][0][v0 + jj];
                        e7[jj] = sm.sh[g][1][v0 + jj];
                    }
                } else {
                    #pragma unroll
                    for (int jj = 0; jj < 8; ++jj) { e6[jj] = 0.f; e7[jj] = 0.f; }
                }
            }

            float ivr[6];
            if (doFin) {
                const float* ivp = inv + (size_t)yr * HP;
                #pragma unroll
                for (int jj = 0; jj < 6; ++jj) {
                    int xr = v0 + jj;
                    ivr[jj] = ivp[xr > 93 ? 93 : xr];   // clamp; garbage masked later
                }
            }

            // ---- diagonal x-taps + y-rotation + finalize yi = y-2 ----
            #pragma unroll
            for (int i = 0; i < 6; ++i) {
                float bv = -INFINITY; int bxr = 0;
                #pragma unroll
                for (int jj = 0; jj < 6; ++jj) {
                    const int i1 = (i + 1 <= 5) ? i + 1 : 0;
                    const int j1 = (jj + 1 <= 5) ? jj + 1 : 0;
                    const int i2 = (i + 2 <= 5) ? i + 2 : 0;
                    const int j2 = (jj + 2 <= 5) ? jj + 2 : 0;
                    float E0 = acc[i][jj];
                    float E1 = (i + 1 <= 5)
                             ? ((jj + 1 <= 5) ? acc[i1][j1] : c6[i1])
                             : e6[jj + 1];
                    float E2 = (i + 2 <= 5)
                             ? ((jj + 2 <= 5) ? acc[i2][j2]
                                              : ((jj + 2 == 6) ? c6[i2] : c7[i2]))
                             : ((i + 2 == 6) ? e6[jj + 2] : e7[jj + 2]);
                    float bx = (E0 + E1) + E2;           // (g0+g1)+g2, as pass2
                    if (doFin) {
                        float v = (pA[i][jj] + bx) * ivr[jj];  // ((B0+B1)+B2)*inv
                        int xr = v0 + jj;
                        if (xr < HP && (u0 + i) < HP && v > bv) { bv = v; bxr = xr; }
                    }
                    if (doA) pA[i][jj] = pB[i][jj] + bx;
                    pB[i][jj] = bx;
                }
                if (doFin) {
                    float mx = bv;
                    #pragma unroll
                    for (int m = 1; m < 16; m <<= 1)
                        mx = fmaxf(mx, __shfl_xor(mx, m));   // 16-lane xr-group max
                    unsigned long long ball = __ballot(bv == mx) & gmask;
                    int srcl = __ffsll(ball) - 1;            // lowest lane = min xr
                    int wxr = __shfl(bxr, srcl);
                    if (tv == 0 && (u0 + i) < HP) {
                        unsigned long long key =
                            ((unsigned long long)fkey(mx) << 32)
                          | (unsigned int)(~(unsigned int)(yr * HP + wxr));
                        const size_t off = (size_t)yi * HP + (u0 + i);
                        if (key > bn[off]) atomicMax(&bn[off], key);  // monotone: stale-skip safe
                    }
                }
            }

            if (doLd) asm volatile("s_waitcnt vmcnt(0)" ::: "memory");
            __syncthreads();   // barrier2: next panels staged in all quarters
        }
    }
}

// ---------------- Kernel 4: expand to 9 shifted copies, channel-interleaved ----------------
__global__ __launch_bounds__(256) void expand_best_kernel(
    const unsigned long long* __restrict__ best, float* __restrict__ out)
{
    int t = blockIdx.x * 256 + threadIdx.x;
    const int total = NITEM * 18 * HW;
    if (t >= total) return;
    int x = t % W;
    int y = (t / W) % H;
    int chn = (t / HW) % 18;
    int n = t / (18 * HW);
    int k = chn >> 1;
    int b = chn & 1;          // 0 -> flow_h, 1 -> flow_w
    int is = k / 3, js = k - is * 3;
    int ys = y - is, xs = x - js;
    float val = 0.f;
    if (ys >= 0 && ys < HP && xs >= 0 && xs < HP) {
        int i = ys * HP + xs;
        unsigned long long key = best[(size_t)n * NP + i];
        int idx = (int)(~(unsigned int)key);
        int yr = idx / HP, xr = idx - yr * HP;
        val = b ? (float)(xr - xs) : (float)(yr - ys);
    }
    out[t] = val;
}

// ---------------- Launch ----------------
extern "C" void kernel_launch(void* const* d_in, const int* in_sizes, int n_in,
                              void* d_out, int out_size, void* d_ws, size_t ws_size,
                              hipStream_t stream) {
    (void)in_sizes; (void)n_in; (void)out_size; (void)ws_size;
    const float* f1 = (const float*)d_in[0];
    const float* f2 = (const float*)d_in[1];

    float2* fiP = (float2*)d_ws;                            // 2*96*32*96 float2 = 4.7 MB
    float2* frP = fiP + (size_t)NITEM * H * 32 * W;         // 4.7 MB
    float*  ssn = (float*)(frP + (size_t)NITEM * H * 32 * W);
    float*  invn = ssn + (size_t)NITEM * HW;
    unsigned long long* best =
        (unsigned long long*)((((uintptr_t)(invn + (size_t)NITEM * NP)) + 63) & ~(uintptr_t)63);
    unsigned int* tick = (unsigned int*)(best + (size_t)NITEM * NP);  // 2 pools, 64B apart
    // total ~9.7 MB of workspace

    normalize_kernel<<<(2 * NITEM * HW + 255) / 256, 256, 0, stream>>>(f1, f2, fiP, frP, ssn);
    refnorm_kernel<<<(NITEM * NP + 255) / 256, 256, 0, stream>>>(ssn, invn);
    hipMemsetAsync(best, 0, (size_t)NITEM * NP * sizeof(unsigned long long) + 512, stream);
    corr_fused_kernel<<<NBLOCKS, 256, 0, stream>>>(fiP, frP, invn, best, tick);
    expand_best_kernel<<<(NITEM * 18 * HW + 255) / 256, 256, 0, stream>>>(best, (float*)d_out);
}